// Round 21
// baseline (105.559 us; speedup 1.0000x reference)
//
#include <hip/hip_runtime.h>
#include <hip/hip_bf16.h>
#include <math.h>

#define B 16
#define V 100000
#define S 4096
#define BS (B * S)      // 65536
#define NT 256          // mfma block threads (4 waves)
#define GRID 1024       // mfma grid (B * 16 jp * 4 iq)
#define NFIN 64         // finisher blocks (last-block distributed reduce)
#define ONE_BF 0x3F80u  // 1.0 in bf16

typedef __attribute__((ext_vector_type(8))) short bf16x8;
typedef __attribute__((ext_vector_type(16))) float f32x16;

static __device__ __forceinline__ unsigned bft(float x) {
  return __float_as_uint(x) >> 16;  // truncating f32 -> bf16 bits
}
static __device__ __forceinline__ float bff(unsigned hbits) {
  return __uint_as_float(hbits << 16);
}
static __device__ __forceinline__ unsigned pk(unsigned lo, unsigned hi) {
  return (lo & 0xFFFFu) | (hi << 16);
}
static __device__ __forceinline__ float min3(float a, float b, float c) {
  return fminf(fminf(a, b), c);  // compiler-fused v_min3_f32 (never inline-asm: R15)
}

// ws layout (floats):
//   part_src[16][BS] @ 0       (4 MB)
//   part_dst[4][BS]  @ 16*BS   (1 MB)
//   counter, flag    @ 20*BS   (re-zeroed by prep every call — replay-safe)
//   srcfrag          @ 21*BS   (2 MB)  B-frags, [tile][lane] uint4
//   dstfrag          @ 29*BS   (2 MB)  A-frags, [point][h] uint4

// ---------------------------------------------------------------------------
// Prep: one point per thread (131072 threads). Thread 0 zeroes out + sync
// cells (graph-replay safe: every call reinitializes).
// ---------------------------------------------------------------------------
__global__ __launch_bounds__(256) void chamfer_prep_kernel(
    const float* __restrict__ src_verts, const float* __restrict__ dst_verts,
    const int* __restrict__ src_idx, const int* __restrict__ dst_idx,
    uint4* __restrict__ srcfrag, uint4* __restrict__ dstfrag,
    unsigned* __restrict__ sync2, float* __restrict__ out) {
  int t = blockIdx.x * 256 + threadIdx.x;  // 0 .. 2*BS-1
  if (t == 0) {
    *out = 0.f;
    sync2[0] = 0u;  // arrival counter
    sync2[1] = 0u;  // release flag
  }
  int set = t >> 16;            // block-uniform
  int i = t & (BS - 1);         // b*S + p
  int b = i >> 12;

  const int* idx = set ? dst_idx : src_idx;
  const float* verts = set ? dst_verts : src_verts;
  int v = idx[i];
  v = v < 0 ? 0 : (v >= V ? V - 1 : v);
  const float* pv = verts + ((size_t)b * V + v) * 3;
  float x = pv[0], y = pv[1], z = pv[2];
  unsigned hx = bft(x), hy = bft(y), hz = bft(z);
  float n2 = x * x + y * y + z * z;
  unsigned n2h = bft(n2);
  unsigned n2l = bft(n2 - bff(n2h));

  if (set == 0) {
    unsigned lx = bft(x - bff(hx)), ly = bft(y - bff(hy)), lz = bft(z - bff(hz));
    int tile = i >> 5, c = i & 31;
    uint4* base = srcfrag + (size_t)tile * 64;
    base[c]      = make_uint4(pk(hx, hy), pk(hz, lx), pk(ly, lz), pk(hx, hy));
    base[32 + c] = make_uint4(pk(hz, n2h), pk(n2l, ONE_BF), pk(ONE_BF, 0u), 0u);
  } else {
    unsigned mx = bft(-2.f * bff(hx)), my = bft(-2.f * bff(hy)), mz = bft(-2.f * bff(hz));
    unsigned nx = bft(-2.f * (x - bff(hx)));
    unsigned ny = bft(-2.f * (y - bff(hy)));
    unsigned nz = bft(-2.f * (z - bff(hz)));
    dstfrag[(size_t)i * 2]     = make_uint4(pk(mx, my), pk(mz, mx), pk(my, mz), pk(nx, ny));
    dstfrag[(size_t)i * 2 + 1] = make_uint4(pk(nz, ONE_BF), pk(ONE_BF, n2h), pk(n2l, 0u), 0u);
  }
}

// ---------------------------------------------------------------------------
// Fused kernel: R19/R20 software-pipelined body + last-block distributed
// reduce. After plane stores: fence -> arrival rank; ranks >= GRID-NFIN are
// finishers (resident by construction: rank>=960 => <=63 blocks unarrived,
// >=192 free CU slots). Rank GRID-1 releases; each finisher folds a disjoint
// 256-float4 slice of the 20 planes and atomicAdds one partial to out.
// ---------------------------------------------------------------------------
__global__ __launch_bounds__(NT, 2) void chamfer_mfma_kernel(
    const uint4* __restrict__ srcfrag, const uint4* __restrict__ dstfrag,
    float* __restrict__ part_src, float* __restrict__ part_dst,
    unsigned* __restrict__ sync2, float* __restrict__ out) {
  __shared__ struct {
    uint4 sfrag[2048];   // 32 KB
    unsigned smin[1024]; // 4 KB
  } sh;
  float* red = (float*)sh.sfrag;  // epilogue overlay (stride-33, 33792 B)

  int bid = blockIdx.x;
  int b = bid >> 6;
  int jp = (bid >> 2) & 15;
  int iq = bid & 3;
  int tid = threadIdx.x;

  // ---- stage: coalesced 32 KB copy
  const uint4* chunk = srcfrag + (size_t)(b * 128 + iq * 32) * 64;
  #pragma unroll
  for (int k = 0; k < 8; ++k) {
    sh.sfrag[tid + k * NT] = chunk[tid + k * NT];
  }
  #pragma unroll
  for (int k = 0; k < 4; ++k) sh.smin[tid + k * NT] = 0x7F800000u;  // +INF

  // ---- A-fragments: two dst tiles per wave, fixed all loop
  int w = tid >> 6;
  int lane = tid & 63;
  int c = lane & 31, h = lane >> 5;
  int gj = b * S + jp * 256 + w * 64 + c;
  bf16x8 A0 = __builtin_bit_cast(bf16x8, dstfrag[(size_t)gj * 2 + h]);
  bf16x8 A1 = __builtin_bit_cast(bf16x8, dstfrag[(size_t)(gj + 32) * 2 + h]);

  __syncthreads();

  f32x16 zero = {};
  f32x16 mn0, mn1;
  #pragma unroll
  for (int r = 0; r < 16; ++r) { mn0[r] = INFINITY; mn1[r] = INFINITY; }

  int t0r = 8 * w;  // per-wave rotation offset

  #define FOLD(dp0, dp1, tp)                                                 \
    {                                                                        \
      _Pragma("unroll")                                                      \
      for (int r = 0; r < 16; ++r) mn0[r] = fminf(mn0[r], dp0[r]);           \
      _Pragma("unroll")                                                      \
      for (int r = 0; r < 16; ++r) mn1[r] = fminf(mn1[r], dp1[r]);           \
      float t0 = min3(dp0[0], dp0[1], dp0[2]);                               \
      float t1 = min3(dp0[3], dp0[4], dp0[5]);                               \
      float t2 = min3(dp0[6], dp0[7], dp0[8]);                               \
      float t3 = min3(dp0[9], dp0[10], dp0[11]);                             \
      float t4 = min3(dp0[12], dp0[13], dp0[14]);                            \
      float u0 = min3(t0, t1, t2);                                           \
      float u1 = min3(t3, t4, dp0[15]);                                      \
      float s0 = min3(dp1[0], dp1[1], dp1[2]);                               \
      float s1 = min3(dp1[3], dp1[4], dp1[5]);                               \
      float s2 = min3(dp1[6], dp1[7], dp1[8]);                               \
      float s3 = min3(dp1[9], dp1[10], dp1[11]);                             \
      float s4 = min3(dp1[12], dp1[13], dp1[14]);                            \
      float v0 = min3(s0, s1, s2);                                           \
      float v1 = min3(s3, s4, dp1[15]);                                      \
      float m = fminf(min3(u0, u1, v0), v1);                                 \
      atomicMin(&sh.smin[(tp) * 32 + c], __float_as_uint(fmaxf(m, 0.f)));    \
    }

  // ---- pipelined main loop: MFMA(t) overlaps FOLD(t-1)
  int tprev = t0r & 31;
  bf16x8 Bf0 = __builtin_bit_cast(bf16x8, sh.sfrag[tprev * 64 + lane]);
  f32x16 dp0 = __builtin_amdgcn_mfma_f32_32x32x16_bf16(A0, Bf0, zero, 0, 0, 0);
  f32x16 dp1 = __builtin_amdgcn_mfma_f32_32x32x16_bf16(A1, Bf0, zero, 0, 0, 0);

  #pragma unroll 4
  for (int it = 1; it < 32; ++it) {
    int t = (it + t0r) & 31;
    bf16x8 Bc = __builtin_bit_cast(bf16x8, sh.sfrag[t * 64 + lane]);
    f32x16 dc0 = __builtin_amdgcn_mfma_f32_32x32x16_bf16(A0, Bc, zero, 0, 0, 0);
    f32x16 dc1 = __builtin_amdgcn_mfma_f32_32x32x16_bf16(A1, Bc, zero, 0, 0, 0);
    FOLD(dp0, dp1, tprev);
    dp0 = dc0;
    dp1 = dc1;
    tprev = t;
  }
  FOLD(dp0, dp1, tprev);
  #undef FOLD

  // ---- src-direction flush
  __syncthreads();
  #pragma unroll
  for (int k = 0; k < 4; ++k) {
    int p = tid + k * NT;
    part_src[jp * BS + b * S + iq * 1024 + p] = __uint_as_float(sh.smin[p]);
  }
  __syncthreads();

  // ---- dst-direction: LDS transpose (stride 33) + fold + store
  #pragma unroll
  for (int r = 0; r < 16; ++r) {
    int row = w * 64 + (r & 3) + 8 * (r >> 2) + 4 * h;  // 32x32 C/D layout
    red[row * 33 + c] = mn0[r];
    red[(row + 32) * 33 + c] = mn1[r];
  }
  __syncthreads();
  {
    int row = tid;
    const float* rp = red + row * 33;
    float a0 = min3(rp[0], rp[1], rp[2]);
    float a1 = min3(rp[3], rp[4], rp[5]);
    float a2 = min3(rp[6], rp[7], rp[8]);
    float a3 = min3(rp[9], rp[10], rp[11]);
    float a4 = min3(rp[12], rp[13], rp[14]);
    float a5 = min3(rp[15], rp[16], rp[17]);
    float a6 = min3(rp[18], rp[19], rp[20]);
    float a7 = min3(rp[21], rp[22], rp[23]);
    float a8 = min3(rp[24], rp[25], rp[26]);
    float a9 = min3(rp[27], rp[28], rp[29]);
    float aa = fminf(rp[30], rp[31]);
    float b0 = min3(a0, a1, a2);
    float b1 = min3(a3, a4, a5);
    float b2 = min3(a6, a7, a8);
    float b3 = min3(a9, aa, b0);
    float m = min3(b1, b2, b3);
    part_dst[iq * BS + b * S + jp * 256 + row] = fmaxf(m, 0.f);
  }

  // ---- last-block distributed reduce -------------------------------------
  __threadfence();  // make this block's plane stores device-visible
  __shared__ unsigned rank_sh;
  if (tid == 0) rank_sh = atomicAdd(&sync2[0], 1u);
  __syncthreads();
  unsigned rank = rank_sh;
  if (rank < GRID - NFIN) return;  // not a finisher

  if (rank == GRID - 1) {          // all 1024 blocks have arrived
    __threadfence();
    atomicExch(&sync2[1], 1u);     // release
  }
  if (tid == 0) {
    while (atomicAdd(&sync2[1], 0u) == 0u) { }  // acquire spin
  }
  __syncthreads();

  {
    int slice = rank - (GRID - NFIN);          // 0..63
    int i4 = slice * NT + tid;                 // 64*256 = 16384 slots = BS
    const float4* ps = (const float4*)part_src;   // 16 src planes
    const float4* pd = (const float4*)part_dst;   // 4 dst planes

    float4 ms = ps[i4];
    #pragma unroll
    for (int j = 1; j < 16; ++j) {
      float4 t = ps[j * (BS / 4) + i4];
      ms.x = fminf(ms.x, t.x); ms.y = fminf(ms.y, t.y);
      ms.z = fminf(ms.z, t.z); ms.w = fminf(ms.w, t.w);
    }
    float4 md = pd[i4];
    #pragma unroll
    for (int j = 1; j < 4; ++j) {
      float4 t = pd[j * (BS / 4) + i4];
      md.x = fminf(md.x, t.x); md.y = fminf(md.y, t.y);
      md.z = fminf(md.z, t.z); md.w = fminf(md.w, t.w);
    }
    float v = (ms.x + ms.y + ms.z + ms.w) + (md.x + md.y + md.z + md.w);
    v *= (1.0f / (float)BS);

    #pragma unroll
    for (int off = 32; off > 0; off >>= 1) v += __shfl_down(v, off, 64);
    __shared__ float fred[4];
    if ((tid & 63) == 0) fred[tid >> 6] = v;
    __syncthreads();
    if (tid == 0) atomicAdd(out, (fred[0] + fred[1]) + (fred[2] + fred[3]));
  }
}

extern "C" void kernel_launch(void* const* d_in, const int* in_sizes, int n_in,
                              void* d_out, int out_size, void* d_ws, size_t ws_size,
                              hipStream_t stream) {
  const float* src_verts = (const float*)d_in[0];
  const float* dst_verts = (const float*)d_in[1];
  const int* src_idx = (const int*)d_in[2];
  const int* dst_idx = (const int*)d_in[3];
  float* out = (float*)d_out;

  float* parts = (float*)d_ws;
  float* part_src = parts;                        // [16][BS]
  float* part_dst = parts + 16 * BS;              // [4][BS]
  unsigned* sync2 = (unsigned*)(parts + 20 * BS); // counter, flag
  uint4* srcfrag = (uint4*)(parts + 21 * BS);     // 2 MB
  uint4* dstfrag = (uint4*)(parts + 29 * BS);     // 2 MB

  chamfer_prep_kernel<<<2 * BS / 256, 256, 0, stream>>>(
      src_verts, dst_verts, src_idx, dst_idx, srcfrag, dstfrag, sync2, out);

  chamfer_mfma_kernel<<<GRID, NT, 0, stream>>>(
      srcfrag, dstfrag, part_src, part_dst, sync2, out);
}

// Round 22
// 28.634 us; speedup vs baseline: 3.6865x; 3.6865x over previous
//
#include <hip/hip_runtime.h>
#include <hip/hip_bf16.h>
#include <math.h>

#define B 16
#define V 100000
#define S 4096
#define BS (B * S)      // 65536
#define NT 256          // mfma block threads (4 waves)
#define ONE_BF 0x3F80u  // 1.0 in bf16

typedef __attribute__((ext_vector_type(8))) short bf16x8;
typedef __attribute__((ext_vector_type(16))) float f32x16;

static __device__ __forceinline__ unsigned bft(float x) {
  return __float_as_uint(x) >> 16;  // truncating f32 -> bf16 bits
}
static __device__ __forceinline__ float bff(unsigned hbits) {
  return __uint_as_float(hbits << 16);
}
static __device__ __forceinline__ unsigned pk(unsigned lo, unsigned hi) {
  return (lo & 0xFFFFu) | (hi << 16);
}
static __device__ __forceinline__ float min3(float a, float b, float c) {
  return fminf(fminf(a, b), c);  // compiler-fused v_min3_f32 (never inline-asm: R15)
}

// ws layout (floats):
//   part_src[16][BS] @ 0       (4 MB)
//   part_dst[4][BS]  @ 16*BS   (1 MB)
//   srcfrag          @ 21*BS   (2 MB)  B-frags, [tile][lane] uint4
//   dstfrag          @ 29*BS   (2 MB)  A-frags, [point][h] uint4
//
// R22 == R20 exactly (revert of R21's in-kernel grid sync, which cost ~70 us
// in device-scope fence/L2-writeback traffic to save a ~2 us launch gap).

// ---------------------------------------------------------------------------
// Prep: one point per thread, 131072 threads (2 waves/SIMD on the
// latency-bound random vertex gather).
// ---------------------------------------------------------------------------
__global__ __launch_bounds__(256) void chamfer_prep_kernel(
    const float* __restrict__ src_verts, const float* __restrict__ dst_verts,
    const int* __restrict__ src_idx, const int* __restrict__ dst_idx,
    uint4* __restrict__ srcfrag, uint4* __restrict__ dstfrag,
    float* __restrict__ out) {
  int t = blockIdx.x * 256 + threadIdx.x;  // 0 .. 2*BS-1
  if (t == 0) *out = 0.f;
  int set = t >> 16;            // block-uniform
  int i = t & (BS - 1);         // b*S + p
  int b = i >> 12;

  const int* idx = set ? dst_idx : src_idx;
  const float* verts = set ? dst_verts : src_verts;
  int v = idx[i];
  v = v < 0 ? 0 : (v >= V ? V - 1 : v);
  const float* pv = verts + ((size_t)b * V + v) * 3;
  float x = pv[0], y = pv[1], z = pv[2];
  unsigned hx = bft(x), hy = bft(y), hz = bft(z);
  float n2 = x * x + y * y + z * z;
  unsigned n2h = bft(n2);
  unsigned n2l = bft(n2 - bff(n2h));

  if (set == 0) {
    unsigned lx = bft(x - bff(hx)), ly = bft(y - bff(hy)), lz = bft(z - bff(hz));
    int tile = i >> 5, c = i & 31;
    uint4* base = srcfrag + (size_t)tile * 64;
    base[c]      = make_uint4(pk(hx, hy), pk(hz, lx), pk(ly, lz), pk(hx, hy));
    base[32 + c] = make_uint4(pk(hz, n2h), pk(n2l, ONE_BF), pk(ONE_BF, 0u), 0u);
  } else {
    unsigned mx = bft(-2.f * bff(hx)), my = bft(-2.f * bff(hy)), mz = bft(-2.f * bff(hz));
    unsigned nx = bft(-2.f * (x - bff(hx)));
    unsigned ny = bft(-2.f * (y - bff(hy)));
    unsigned nz = bft(-2.f * (z - bff(hz)));
    dstfrag[(size_t)i * 2]     = make_uint4(pk(mx, my), pk(mz, mx), pk(my, mz), pk(nx, ny));
    dstfrag[(size_t)i * 2 + 1] = make_uint4(pk(nz, ONE_BF), pk(ONE_BF, n2h), pk(n2l, 0u), 0u);
  }
}

// ---------------------------------------------------------------------------
// Fused kernel: software-pipelined body (MFMA(t) overlaps FOLD(t-1)).
// ---------------------------------------------------------------------------
__global__ __launch_bounds__(NT, 2) void chamfer_mfma_kernel(
    const uint4* __restrict__ srcfrag, const uint4* __restrict__ dstfrag,
    float* __restrict__ part_src, float* __restrict__ part_dst) {
  __shared__ struct {
    uint4 sfrag[2048];   // 32 KB
    unsigned smin[1024]; // 4 KB
  } sh;
  float* red = (float*)sh.sfrag;  // epilogue overlay (stride-33, 33792 B)

  int bid = blockIdx.x;
  int b = bid >> 6;
  int jp = (bid >> 2) & 15;
  int iq = bid & 3;
  int tid = threadIdx.x;

  // ---- stage: coalesced 32 KB copy
  const uint4* chunk = srcfrag + (size_t)(b * 128 + iq * 32) * 64;
  #pragma unroll
  for (int k = 0; k < 8; ++k) {
    sh.sfrag[tid + k * NT] = chunk[tid + k * NT];
  }
  #pragma unroll
  for (int k = 0; k < 4; ++k) sh.smin[tid + k * NT] = 0x7F800000u;  // +INF

  // ---- A-fragments: two dst tiles per wave, fixed all loop
  int w = tid >> 6;
  int lane = tid & 63;
  int c = lane & 31, h = lane >> 5;
  int gj = b * S + jp * 256 + w * 64 + c;
  bf16x8 A0 = __builtin_bit_cast(bf16x8, dstfrag[(size_t)gj * 2 + h]);
  bf16x8 A1 = __builtin_bit_cast(bf16x8, dstfrag[(size_t)(gj + 32) * 2 + h]);

  __syncthreads();

  f32x16 zero = {};
  f32x16 mn0, mn1;
  #pragma unroll
  for (int r = 0; r < 16; ++r) { mn0[r] = INFINITY; mn1[r] = INFINITY; }

  int t0r = 8 * w;  // per-wave rotation offset

  #define FOLD(dp0, dp1, tp)                                                 \
    {                                                                        \
      _Pragma("unroll")                                                      \
      for (int r = 0; r < 16; ++r) mn0[r] = fminf(mn0[r], dp0[r]);           \
      _Pragma("unroll")                                                      \
      for (int r = 0; r < 16; ++r) mn1[r] = fminf(mn1[r], dp1[r]);           \
      float t0 = min3(dp0[0], dp0[1], dp0[2]);                               \
      float t1 = min3(dp0[3], dp0[4], dp0[5]);                               \
      float t2 = min3(dp0[6], dp0[7], dp0[8]);                               \
      float t3 = min3(dp0[9], dp0[10], dp0[11]);                             \
      float t4 = min3(dp0[12], dp0[13], dp0[14]);                            \
      float u0 = min3(t0, t1, t2);                                           \
      float u1 = min3(t3, t4, dp0[15]);                                      \
      float s0 = min3(dp1[0], dp1[1], dp1[2]);                               \
      float s1 = min3(dp1[3], dp1[4], dp1[5]);                               \
      float s2 = min3(dp1[6], dp1[7], dp1[8]);                               \
      float s3 = min3(dp1[9], dp1[10], dp1[11]);                             \
      float s4 = min3(dp1[12], dp1[13], dp1[14]);                            \
      float v0 = min3(s0, s1, s2);                                           \
      float v1 = min3(s3, s4, dp1[15]);                                      \
      float m = fminf(min3(u0, u1, v0), v1);                                 \
      atomicMin(&sh.smin[(tp) * 32 + c], __float_as_uint(fmaxf(m, 0.f)));    \
    }

  // ---- pipelined main loop: MFMA(t) overlaps FOLD(t-1)
  int tprev = t0r & 31;
  bf16x8 Bf0 = __builtin_bit_cast(bf16x8, sh.sfrag[tprev * 64 + lane]);
  f32x16 dp0 = __builtin_amdgcn_mfma_f32_32x32x16_bf16(A0, Bf0, zero, 0, 0, 0);
  f32x16 dp1 = __builtin_amdgcn_mfma_f32_32x32x16_bf16(A1, Bf0, zero, 0, 0, 0);

  #pragma unroll 4
  for (int it = 1; it < 32; ++it) {
    int t = (it + t0r) & 31;
    bf16x8 Bc = __builtin_bit_cast(bf16x8, sh.sfrag[t * 64 + lane]);
    f32x16 dc0 = __builtin_amdgcn_mfma_f32_32x32x16_bf16(A0, Bc, zero, 0, 0, 0);
    f32x16 dc1 = __builtin_amdgcn_mfma_f32_32x32x16_bf16(A1, Bc, zero, 0, 0, 0);
    FOLD(dp0, dp1, tprev);
    dp0 = dc0;
    dp1 = dc1;
    tprev = t;
  }
  FOLD(dp0, dp1, tprev);
  #undef FOLD

  // ---- src-direction flush
  __syncthreads();
  #pragma unroll
  for (int k = 0; k < 4; ++k) {
    int p = tid + k * NT;
    part_src[jp * BS + b * S + iq * 1024 + p] = __uint_as_float(sh.smin[p]);
  }
  __syncthreads();

  // ---- dst-direction: LDS transpose (stride 33) + fold + store
  #pragma unroll
  for (int r = 0; r < 16; ++r) {
    int row = w * 64 + (r & 3) + 8 * (r >> 2) + 4 * h;  // 32x32 C/D layout
    red[row * 33 + c] = mn0[r];
    red[(row + 32) * 33 + c] = mn1[r];
  }
  __syncthreads();
  {
    int row = tid;
    const float* rp = red + row * 33;
    float a0 = min3(rp[0], rp[1], rp[2]);
    float a1 = min3(rp[3], rp[4], rp[5]);
    float a2 = min3(rp[6], rp[7], rp[8]);
    float a3 = min3(rp[9], rp[10], rp[11]);
    float a4 = min3(rp[12], rp[13], rp[14]);
    float a5 = min3(rp[15], rp[16], rp[17]);
    float a6 = min3(rp[18], rp[19], rp[20]);
    float a7 = min3(rp[21], rp[22], rp[23]);
    float a8 = min3(rp[24], rp[25], rp[26]);
    float a9 = min3(rp[27], rp[28], rp[29]);
    float aa = fminf(rp[30], rp[31]);
    float b0 = min3(a0, a1, a2);
    float b1 = min3(a3, a4, a5);
    float b2 = min3(a6, a7, a8);
    float b3 = min3(a9, aa, b0);
    float m = min3(b1, b2, b3);
    part_dst[iq * BS + b * S + jp * 256 + row] = fmaxf(m, 0.f);
  }
}

// ---------------------------------------------------------------------------
// Reduce: 64 blocks x 256 threads, fold 16 src + 4 dst planes, one atomicAdd
// per block (64 total — cheap per R7).
// ---------------------------------------------------------------------------
__global__ __launch_bounds__(256) void chamfer_reduce_kernel(
    const float* __restrict__ parts, float* __restrict__ out) {
  __shared__ float red[4];
  int tid = threadIdx.x;
  const float4* ps = (const float4*)parts;             // 16 src planes
  const float4* pd = (const float4*)(parts + 16 * BS); // 4 dst planes

  float v = 0.f;
  int t4 = blockIdx.x * 256 + tid;
  if (t4 < BS / 4) {
    float4 ms = ps[t4];
    #pragma unroll
    for (int j = 1; j < 16; ++j) {
      float4 t = ps[j * (BS / 4) + t4];
      ms.x = fminf(ms.x, t.x); ms.y = fminf(ms.y, t.y);
      ms.z = fminf(ms.z, t.z); ms.w = fminf(ms.w, t.w);
    }
    float4 md = pd[t4];
    #pragma unroll
    for (int j = 1; j < 4; ++j) {
      float4 t = pd[j * (BS / 4) + t4];
      md.x = fminf(md.x, t.x); md.y = fminf(md.y, t.y);
      md.z = fminf(md.z, t.z); md.w = fminf(md.w, t.w);
    }
    v = (ms.x + ms.y + ms.z + ms.w) + (md.x + md.y + md.z + md.w);
    v *= (1.0f / (float)BS);
  }

  #pragma unroll
  for (int off = 32; off > 0; off >>= 1) v += __shfl_down(v, off, 64);
  if ((tid & 63) == 0) red[tid >> 6] = v;
  __syncthreads();
  if (tid == 0) atomicAdd(out, (red[0] + red[1]) + (red[2] + red[3]));
}

extern "C" void kernel_launch(void* const* d_in, const int* in_sizes, int n_in,
                              void* d_out, int out_size, void* d_ws, size_t ws_size,
                              hipStream_t stream) {
  const float* src_verts = (const float*)d_in[0];
  const float* dst_verts = (const float*)d_in[1];
  const int* src_idx = (const int*)d_in[2];
  const int* dst_idx = (const int*)d_in[3];
  float* out = (float*)d_out;

  float* parts = (float*)d_ws;
  float* part_src = parts;                        // [16][BS]
  float* part_dst = parts + 16 * BS;              // [4][BS]
  uint4* srcfrag = (uint4*)(parts + 21 * BS);     // 2 MB
  uint4* dstfrag = (uint4*)(parts + 29 * BS);     // 2 MB

  chamfer_prep_kernel<<<2 * BS / 256, 256, 0, stream>>>(
      src_verts, dst_verts, src_idx, dst_idx, srcfrag, dstfrag, out);

  chamfer_mfma_kernel<<<B * 16 * 4, NT, 0, stream>>>(
      srcfrag, dstfrag, part_src, part_dst);

  chamfer_reduce_kernel<<<64, 256, 0, stream>>>(parts, out);
}